// Round 2
// baseline (3877.064 us; speedup 1.0000x reference)
//
#include <hip/hip_runtime.h>
#include <math.h>

// Mamba2: D_MODEL=1024, EXPAND=2, HEADDIM=64, NGROUPS=1, D_STATE=64,
// D_CONV=4, CHUNK=64, B=4, L=4096.  Per-batch pipeline (L rows at a time).
#define BATCH  4
#define LSEQ   4096
#define DMODEL 1024
#define DINNER 2048
#define NH     32
#define HD     64
#define DSTATE 64
#define CONVD  2176      // D_INNER + 2*D_STATE
#define NXD    2208      // CONVD + NH (xBC + dt columns of in_proj)
#define NCHUNK 64        // LSEQ / 64

__device__ __forceinline__ float sigm(float x){ return 1.f/(1.f+expf(-x)); }

// ---------------------------------------------------------------------------
// GEMM NT: C[M,N] = A[M,K] * B[N,K]^T (row-major, K contiguous).
// 128x128 tile, BK=16, 256 threads, 8x8 per thread.
// EPI=0: plain store. EPI=1: xBC+dt epilogue (xbc store + conv-halo save +
//        softplus dt); assumes M=4096 (one batch), N=2208, col 0 == in_proj
//        col 2048.
// ---------------------------------------------------------------------------
template<int EPI>
__global__ __launch_bounds__(256)
void gemm_nt(const float* __restrict__ A, const float* __restrict__ B,
             float* __restrict__ C, int M, int N, int K,
             float* __restrict__ xbcout, float* __restrict__ dtout,
             const float* __restrict__ dt_bias, float* __restrict__ halo)
{
    constexpr int BM=128, BN=128, BK=16;
    __shared__ alignas(16) float As[BK][BM+4];
    __shared__ alignas(16) float Bs[BK][BN+4];
    const int tid = threadIdx.x;
    const int bm = blockIdx.y * BM;
    const int bn = blockIdx.x * BN;
    const int ty = tid >> 4, tx = tid & 15;
    const int r0 = ty*8, c0 = tx*8;
    float acc[8][8];
    #pragma unroll
    for (int i=0;i<8;i++)
        #pragma unroll
        for (int j=0;j<8;j++) acc[i][j]=0.f;

    for (int k0=0;k0<K;k0+=BK){
        #pragma unroll
        for (int it=0; it<2; it++){
            int idx = tid + it*256;
            int row = idx >> 2;              // 0..127
            int k4  = (idx & 3) << 2;        // 0,4,8,12
            float4 av = *(const float4*)(A + (size_t)(bm+row)*K + k0 + k4);
            As[k4+0][row]=av.x; As[k4+1][row]=av.y; As[k4+2][row]=av.z; As[k4+3][row]=av.w;
            int nrow = bn + row;
            float4 bv = make_float4(0.f,0.f,0.f,0.f);
            if (nrow < N) bv = *(const float4*)(B + (size_t)nrow*K + k0 + k4);
            Bs[k4+0][row]=bv.x; Bs[k4+1][row]=bv.y; Bs[k4+2][row]=bv.z; Bs[k4+3][row]=bv.w;
        }
        __syncthreads();
        #pragma unroll
        for (int k=0;k<BK;k++){
            float4 a0 = *(const float4*)&As[k][r0];
            float4 a1 = *(const float4*)&As[k][r0+4];
            float4 b0 = *(const float4*)&Bs[k][c0];
            float4 b1 = *(const float4*)&Bs[k][c0+4];
            float av[8] = {a0.x,a0.y,a0.z,a0.w,a1.x,a1.y,a1.z,a1.w};
            float bv[8] = {b0.x,b0.y,b0.z,b0.w,b1.x,b1.y,b1.z,b1.w};
            #pragma unroll
            for (int i=0;i<8;i++)
                #pragma unroll
                for (int j=0;j<8;j++)
                    acc[i][j] = fmaf(av[i], bv[j], acc[i][j]);
        }
        __syncthreads();
    }

    if (EPI == 0){
        #pragma unroll
        for (int i=0;i<8;i++){
            int m = bm + r0 + i;
            float* cr = C + (size_t)m*N;
            #pragma unroll
            for (int j4=0;j4<2;j4++){
                int n = bn + c0 + j4*4;
                *(float4*)(cr + n) = make_float4(acc[i][j4*4+0],acc[i][j4*4+1],
                                                 acc[i][j4*4+2],acc[i][j4*4+3]);
            }
        }
    } else {
        // CONVD=2176 = 17*128 -> tiles 0..16 are xBC, tile 17 is dt.
        if (bn < CONVD){
            #pragma unroll
            for (int i=0;i<8;i++){
                int l = bm + r0 + i;          // per-batch row == timestep
                int col = bn + c0;
                float4 v0 = make_float4(acc[i][0],acc[i][1],acc[i][2],acc[i][3]);
                float4 v1 = make_float4(acc[i][4],acc[i][5],acc[i][6],acc[i][7]);
                float* xr = xbcout + (size_t)l*CONVD + col;
                *(float4*)(xr)   = v0;
                *(float4*)(xr+4) = v1;
                int rel = l & 63;
                if (rel >= 61){               // save pre-conv halo for next segment
                    int seg = (l >> 6) + 1;
                    if (seg < NCHUNK){
                        float* hp = halo + ((size_t)(seg*3 + (rel-61)))*CONVD + col;
                        *(float4*)(hp)   = v0;
                        *(float4*)(hp+4) = v1;
                    }
                }
            }
        } else {
            // dt columns: local h = c0+j (tile-local), valid for h < 32
            #pragma unroll
            for (int i=0;i<8;i++){
                int l = bm + r0 + i;
                #pragma unroll
                for (int j=0;j<8;j++){
                    int h = c0 + j;
                    if (h < NH){
                        float t = acc[i][j] + dt_bias[h];
                        dtout[(size_t)l*NH + h] = (t > 20.f) ? t : log1pf(expf(t));
                    }
                }
            }
        }
    }
}

// ---------------------------------------------------------------------------
// Causal depthwise conv(4) + bias + SiLU, IN PLACE over xbc using pre-saved
// halos.  One thread per (channel, 64-step segment).
// ---------------------------------------------------------------------------
__global__ __launch_bounds__(256)
void conv_inplace(float* __restrict__ xbc, const float* __restrict__ halo,
                  const float* __restrict__ conv_w, const float* __restrict__ conv_b)
{
    int c = blockIdx.x*256 + threadIdx.x;
    if (c >= CONVD) return;
    int seg = blockIdx.y;           // 0..63
    const float w0=conv_w[c*4+0], w1=conv_w[c*4+1], w2=conv_w[c*4+2], w3=conv_w[c*4+3];
    const float bias = conv_b[c];
    float x0=0.f, x1=0.f, x2=0.f;
    if (seg > 0){
        const float* hp = halo + (size_t)(seg*3)*CONVD + c;
        x0 = hp[0]; x1 = hp[CONVD]; x2 = hp[2*CONVD];
    }
    float* p = xbc + (size_t)(seg*64)*CONVD + c;
    for (int i=0;i<64;i++){
        float x3 = *p;
        float v = fmaf(w0,x0,fmaf(w1,x1,fmaf(w2,x2,fmaf(w3,x3,bias))));
        *p = v * sigm(v);
        x0=x1; x1=x2; x2=x3; p += CONVD;
    }
}

// ---------------------------------------------------------------------------
// Intra-chunk (per batch): grid (chunk c, head h).
//  score = (C B^T) .* exp(segsum), Y_diag = score @ X (X = x*dt),
//  local_state[p,n] = sum_l B[l,n]*exp(acs63-acs[l])*X[l,p],
//  writes (Y_diag + x*D) in place over the x-region of xbc.
// ---------------------------------------------------------------------------
__global__ __launch_bounds__(256)
void chunk_intra(float* __restrict__ xbc,
                 const float* __restrict__ dtbuf,
                 const float* __restrict__ A_log,
                 const float* __restrict__ Dvec,
                 float* __restrict__ states,
                 float* __restrict__ acsbuf,
                 float* __restrict__ csumbuf)
{
    const int c = blockIdx.x, h = blockIdx.y;
    __shared__ alignas(16) float CS[64][68];   // C tile, then reused for score
    __shared__ alignas(16) float Bsh[64][68];
    __shared__ alignas(16) float Xsh[64][68];
    __shared__ float dt_sh[64];
    __shared__ float acs[64];
    __shared__ float dec_sh[64];
    const int tid = threadIdx.x;
    const size_t row0 = (size_t)(c*64) * CONVD;

    if (tid < 64) dt_sh[tid] = dtbuf[(size_t)(c*64 + tid)*NH + h];
    __syncthreads();
    if (tid == 0){
        float Ah = -expf(A_log[h]);
        float s = 0.f;
        for (int l=0;l<64;l++){ s = fmaf(Ah, dt_sh[l], s); acs[l] = s; }
    }
    {
        const int lr = tid >> 4;
        const int n4 = (tid & 15) * 4;
        #pragma unroll
        for (int i=0;i<4;i++){
            int l = lr + i*16;
            const float* rp = xbc + row0 + (size_t)l*CONVD;
            float4 cv = *(const float4*)(rp + DINNER + DSTATE + n4);  // C cols
            float4 bv = *(const float4*)(rp + DINNER + n4);           // B cols
            float4 xv = *(const float4*)(rp + h*HD + n4);             // x cols
            float d = dt_sh[l];
            *(float4*)&CS[l][n4]  = cv;
            *(float4*)&Bsh[l][n4] = bv;
            *(float4*)&Xsh[l][n4] = make_float4(xv.x*d, xv.y*d, xv.z*d, xv.w*d);
        }
    }
    __syncthreads();
    const float acs63 = acs[63];
    if (tid < 64){
        dec_sh[tid] = expf(acs63 - acs[tid]);
        acsbuf[((size_t)h*64 + c)*64 + tid] = acs[tid];
    }
    if (tid == 0) csumbuf[(size_t)h*64 + c] = acs63;

    const int ty = tid >> 4, tx = tid & 15;
    const int l0 = ty*4, s0 = tx*4;

    // G = C B^T
    float g[4][4] = {{0.f}};
    #pragma unroll 2
    for (int n=0;n<64;n+=4){
        float4 ca[4], bb[4];
        #pragma unroll
        for (int i=0;i<4;i++) ca[i] = *(const float4*)&CS[l0+i][n];
        #pragma unroll
        for (int j=0;j<4;j++) bb[j] = *(const float4*)&Bsh[s0+j][n];
        #pragma unroll
        for (int i=0;i<4;i++)
            #pragma unroll
            for (int j=0;j<4;j++)
                g[i][j] += ca[i].x*bb[j].x + ca[i].y*bb[j].y + ca[i].z*bb[j].z + ca[i].w*bb[j].w;
    }
    __syncthreads();            // all reads of C tile done
    #pragma unroll
    for (int i=0;i<4;i++){
        int l = l0 + i;
        #pragma unroll
        for (int j=0;j<4;j++){
            int s = s0 + j;
            CS[l][s] = (s <= l) ? g[i][j]*expf(acs[l]-acs[s]) : 0.f;
        }
    }
    __syncthreads();

    // Y_diag[l,p] = sum_s score[l,s] * X[s,p]
    float yd[4][4] = {{0.f}};
    #pragma unroll 4
    for (int s=0;s<64;s++){
        float4 xv = *(const float4*)&Xsh[s][s0];
        float sc[4];
        #pragma unroll
        for (int i=0;i<4;i++) sc[i] = CS[l0+i][s];
        #pragma unroll
        for (int i=0;i<4;i++){
            yd[i][0] = fmaf(sc[i], xv.x, yd[i][0]);
            yd[i][1] = fmaf(sc[i], xv.y, yd[i][1]);
            yd[i][2] = fmaf(sc[i], xv.z, yd[i][2]);
            yd[i][3] = fmaf(sc[i], xv.w, yd[i][3]);
        }
    }

    // local_state[p,n] = sum_l dec[l]*X[l,p]*B[l,n]
    float st[4][4] = {{0.f}};
    #pragma unroll 4
    for (int l=0;l<64;l++){
        float w = dec_sh[l];
        float4 xv = *(const float4*)&Xsh[l][l0];
        float4 bv = *(const float4*)&Bsh[l][s0];
        float wx0 = w*xv.x, wx1 = w*xv.y, wx2 = w*xv.z, wx3 = w*xv.w;
        st[0][0]=fmaf(wx0,bv.x,st[0][0]); st[0][1]=fmaf(wx0,bv.y,st[0][1]);
        st[0][2]=fmaf(wx0,bv.z,st[0][2]); st[0][3]=fmaf(wx0,bv.w,st[0][3]);
        st[1][0]=fmaf(wx1,bv.x,st[1][0]); st[1][1]=fmaf(wx1,bv.y,st[1][1]);
        st[1][2]=fmaf(wx1,bv.z,st[1][2]); st[1][3]=fmaf(wx1,bv.w,st[1][3]);
        st[2][0]=fmaf(wx2,bv.x,st[2][0]); st[2][1]=fmaf(wx2,bv.y,st[2][1]);
        st[2][2]=fmaf(wx2,bv.z,st[2][2]); st[2][3]=fmaf(wx2,bv.w,st[2][3]);
        st[3][0]=fmaf(wx3,bv.x,st[3][0]); st[3][1]=fmaf(wx3,bv.y,st[3][1]);
        st[3][2]=fmaf(wx3,bv.z,st[3][2]); st[3][3]=fmaf(wx3,bv.w,st[3][3]);
    }
    const size_t sbase = ((size_t)c*NH + h)*4096;
    #pragma unroll
    for (int i=0;i<4;i++)
        *(float4*)(states + sbase + (size_t)(l0+i)*64 + s0) =
            make_float4(st[i][0],st[i][1],st[i][2],st[i][3]);

    // write partial Y = Y_diag + x*D over x-region (exclusive per (c,h))
    const float Dh = Dvec[h];
    #pragma unroll
    for (int i=0;i<4;i++){
        int l = l0 + i;
        float* rp = xbc + row0 + (size_t)l*CONVD + h*HD + s0;
        float4 xo = *(const float4*)rp;
        *(float4*)rp = make_float4(fmaf(xo.x,Dh,yd[i][0]),
                                   fmaf(xo.y,Dh,yd[i][1]),
                                   fmaf(xo.z,Dh,yd[i][2]),
                                   fmaf(xo.w,Dh,yd[i][3]));
    }
}

// ---------------------------------------------------------------------------
// Inter-chunk scan (per batch): grid (h).  In-place: local -> entering states.
// ---------------------------------------------------------------------------
__global__ __launch_bounds__(256)
void chunk_scan(float* __restrict__ states, const float* __restrict__ csumbuf,
                const float* __restrict__ init_states)
{
    const int h = blockIdx.x;
    __shared__ float cs_sh[64];
    const int tid = threadIdx.x;
    if (tid < 64) cs_sh[tid] = csumbuf[(size_t)h*64 + tid];
    __syncthreads();
    float4 S[4];
    const float4* ip = (const float4*)(init_states + (size_t)h*4096);
    #pragma unroll
    for (int j=0;j<4;j++) S[j] = ip[tid + j*256];
    for (int z=0; z<NCHUNK; z++){
        float4* sp = (float4*)(states + ((size_t)z*NH + h)*4096);
        float dec = expf(cs_sh[z]);
        #pragma unroll
        for (int j=0;j<4;j++){
            int idx = tid + j*256;
            float4 loc = sp[idx];
            float4 cur = S[j];
            sp[idx] = cur;                       // entering state of chunk z
            S[j].x = fmaf(dec, cur.x, loc.x);
            S[j].y = fmaf(dec, cur.y, loc.y);
            S[j].z = fmaf(dec, cur.z, loc.z);
            S[j].w = fmaf(dec, cur.w, loc.w);
        }
    }
}

// ---------------------------------------------------------------------------
// Y_off (per batch): grid (c,h).  Y[l,p] += exp(acs[l]) * sum_n C[l,n]*S[p,n]
// ---------------------------------------------------------------------------
__global__ __launch_bounds__(256)
void chunk_off(float* __restrict__ xbc,
               const float* __restrict__ states,
               const float* __restrict__ acsbuf)
{
    const int c = blockIdx.x, h = blockIdx.y;
    __shared__ alignas(16) float Csh[64][68];
    __shared__ alignas(16) float Ssh[64][68];
    __shared__ float ea[64];
    const int tid = threadIdx.x;
    const size_t row0 = (size_t)(c*64) * CONVD;
    const size_t sbase = ((size_t)c*NH + h)*4096;
    {
        const int lr = tid >> 4;
        const int n4 = (tid & 15)*4;
        #pragma unroll
        for (int i=0;i<4;i++){
            int r = lr + i*16;
            *(float4*)&Csh[r][n4] = *(const float4*)(xbc + row0 + (size_t)r*CONVD + DINNER + DSTATE + n4);
            *(float4*)&Ssh[r][n4] = *(const float4*)(states + sbase + (size_t)r*64 + n4);
        }
    }
    if (tid < 64) ea[tid] = expf(acsbuf[((size_t)h*64 + c)*64 + tid]);
    __syncthreads();
    const int ty = tid >> 4, tx = tid & 15;
    const int l0 = ty*4, p0 = tx*4;
    float yo[4][4] = {{0.f}};
    #pragma unroll 2
    for (int n=0;n<64;n+=4){
        float4 cv[4], sv[4];
        #pragma unroll
        for (int i=0;i<4;i++) cv[i] = *(const float4*)&Csh[l0+i][n];
        #pragma unroll
        for (int j=0;j<4;j++) sv[j] = *(const float4*)&Ssh[p0+j][n];
        #pragma unroll
        for (int i=0;i<4;i++)
            #pragma unroll
            for (int j=0;j<4;j++)
                yo[i][j] += cv[i].x*sv[j].x + cv[i].y*sv[j].y + cv[i].z*sv[j].z + cv[i].w*sv[j].w;
    }
    #pragma unroll
    for (int i=0;i<4;i++){
        int l = l0 + i;
        float e = ea[l];
        float* rp = xbc + row0 + (size_t)l*CONVD + h*HD + p0;
        float4 o = *(const float4*)rp;
        *(float4*)rp = make_float4(fmaf(e,yo[i][0],o.x), fmaf(e,yo[i][1],o.y),
                                   fmaf(e,yo[i][2],o.z), fmaf(e,yo[i][3],o.w));
    }
}

// ---------------------------------------------------------------------------
// gating (y = Y * silu(z)) + RMSNorm, per row; writes over z buffer
// ---------------------------------------------------------------------------
__global__ __launch_bounds__(256)
void gate_norm(const float* __restrict__ xbc, float* __restrict__ zbuf,
               const float* __restrict__ norm_w)
{
    const int m = blockIdx.x;
    const int tid = threadIdx.x;
    const float4* Yrow = (const float4*)(xbc + (size_t)m*CONVD);
    float4* zrow = (float4*)(zbuf + (size_t)m*DINNER);
    float4 yv[2];
    float acc = 0.f;
    #pragma unroll
    for (int j=0;j<2;j++){
        int f = tid + j*256;
        float4 Y = Yrow[f];
        float4 z = zrow[f];
        float4 g;
        g.x = Y.x * z.x * sigm(z.x);
        g.y = Y.y * z.y * sigm(z.y);
        g.z = Y.z * z.z * sigm(z.z);
        g.w = Y.w * z.w * sigm(z.w);
        yv[j] = g;
        acc += g.x*g.x + g.y*g.y + g.z*g.z + g.w*g.w;
    }
    #pragma unroll
    for (int o=32;o>0;o>>=1) acc += __shfl_down(acc, o, 64);
    __shared__ float red[4];
    if ((tid & 63)==0) red[tid>>6] = acc;
    __syncthreads();
    float tot = red[0]+red[1]+red[2]+red[3];
    float scale = rsqrtf(tot * (1.f/2048.f) + 1e-5f);
    const float4* nw = (const float4*)norm_w;
    #pragma unroll
    for (int j=0;j<2;j++){
        int f = tid + j*256;
        float4 w = nw[f];
        float4 g = yv[j];
        zrow[f] = make_float4(g.x*scale*w.x, g.y*scale*w.y, g.z*scale*w.z, g.w*scale*w.w);
    }
}

// ---------------------------------------------------------------------------
extern "C" void kernel_launch(void* const* d_in, const int* in_sizes, int n_in,
                              void* d_out, int out_size, void* d_ws, size_t ws_size,
                              hipStream_t stream) {
    const float* u           = (const float*)d_in[0];
    const float* in_proj_w   = (const float*)d_in[1];
    const float* conv_w      = (const float*)d_in[2];
    const float* conv_b      = (const float*)d_in[3];
    const float* init_states = (const float*)d_in[4];
    const float* dt_bias     = (const float*)d_in[5];
    const float* A_log       = (const float*)d_in[6];
    const float* Dv          = (const float*)d_in[7];
    const float* norm_w      = (const float*)d_in[8];
    const float* out_proj_w  = (const float*)d_in[9];
    float* out = (float*)d_out;

    // Per-batch workspace (reused across the 4 batches), floats:
    //  xbc   4096*2176 = 8,912,896   (pre-conv xBC -> activations -> Y in place)
    //  zbuf  4096*2048 = 8,388,608   (aliases states: z written after chunk_off)
    //  dtbuf 4096*32, acs 32*64*64, csum 32*64, halo 64*3*2176
    //  total ~ 72 MB
    float* ws = (float*)d_ws;
    size_t off = 0;
    float* xbc     = ws + off; off += (size_t)LSEQ*CONVD;
    float* zbuf    = ws + off; off += (size_t)LSEQ*DINNER;   // union with states
    float* dtbuf   = ws + off; off += (size_t)LSEQ*NH;
    float* acsbuf  = ws + off; off += (size_t)NH*NCHUNK*64;
    float* csumbuf = ws + off; off += (size_t)NH*NCHUNK;
    float* halo    = ws + off; off += (size_t)NCHUNK*3*CONVD;
    float* states  = zbuf;   // states dead before z-GEMM writes zbuf

    const float* Bw_xbcdt = in_proj_w + (size_t)DINNER*DMODEL;  // rows 2048..4255
    const float* Bw_z     = in_proj_w;                          // rows 0..2047

    for (int b=0; b<BATCH; b++){
        const float* ub   = u   + (size_t)b*LSEQ*DMODEL;
        float*       outb = out + (size_t)b*LSEQ*DMODEL;

        // 1) in_proj xBC+dt columns (+ conv-halo save, softplus dt)
        gemm_nt<1><<<dim3((NXD+127)/128, LSEQ/128), 256, 0, stream>>>(
            ub, Bw_xbcdt, nullptr, LSEQ, NXD, DMODEL, xbc, dtbuf, dt_bias, halo);
        // 2) causal conv + silu, in place
        conv_inplace<<<dim3((CONVD+255)/256, NCHUNK), 256, 0, stream>>>(
            xbc, halo, conv_w, conv_b);
        // 3) intra-chunk (Y_diag + x*D in place, local states, acs)
        chunk_intra<<<dim3(NCHUNK, NH), 256, 0, stream>>>(
            xbc, dtbuf, A_log, Dv, states, acsbuf, csumbuf);
        // 4) inter-chunk scan (in place -> entering states)
        chunk_scan<<<dim3(NH), 256, 0, stream>>>(states, csumbuf, init_states);
        // 5) Y_off accumulate in place
        chunk_off<<<dim3(NCHUNK, NH), 256, 0, stream>>>(xbc, states, acsbuf);
        // 6) in_proj z columns (states now dead; zbuf aliases it)
        gemm_nt<0><<<dim3(DINNER/128, LSEQ/128), 256, 0, stream>>>(
            ub, Bw_z, zbuf, LSEQ, DINNER, DMODEL, nullptr, nullptr, nullptr, nullptr);
        // 7) gate + RMSNorm (writes over zbuf)
        gate_norm<<<dim3(LSEQ), 256, 0, stream>>>(xbc, zbuf, norm_w);
        // 8) out_proj -> out
        gemm_nt<0><<<dim3(DMODEL/128, LSEQ/128), 256, 0, stream>>>(
            zbuf, out_proj_w, outb, LSEQ, DMODEL, DINNER, nullptr, nullptr, nullptr, nullptr);
    }
}

// Round 3
// 1190.931 us; speedup vs baseline: 3.2555x; 3.2555x over previous
//
#include <hip/hip_runtime.h>
#include <math.h>

// Mamba2: D_MODEL=1024, EXPAND=2, HEADDIM=64, NGROUPS=1, D_STATE=64,
// D_CONV=4, CHUNK=64, B=4, L=4096.  Per-batch pipeline, bf16 MFMA GEMMs.
#define BATCH  4
#define LSEQ   4096
#define DMODEL 1024
#define DINNER 2048
#define NH     32
#define HD     64
#define DSTATE 64
#define CONVD  2176      // D_INNER + 2*D_STATE
#define NXD    2208      // CONVD + NH
#define NCHUNK 64

typedef __attribute__((ext_vector_type(8))) short bf16x8;
typedef __attribute__((ext_vector_type(4))) float f32x4;

__device__ __forceinline__ float sigm(float x){ return 1.f/(1.f+expf(-x)); }

__device__ __forceinline__ unsigned short f2bf(float x){
    unsigned u = __float_as_uint(x);
    unsigned r = (u + 0x7fffu + ((u>>16)&1u)) >> 16;
    return (unsigned short)r;
}
__device__ __forceinline__ float bf2f(unsigned short h){
    return __uint_as_float(((unsigned)h)<<16);
}

// async global (16B/lane) -> LDS (wave-uniform base + lane*16)
__device__ __forceinline__ void gl2lds16(const unsigned short* g, short* l){
    __builtin_amdgcn_global_load_lds(
        (const __attribute__((address_space(1))) unsigned int*)g,
        (__attribute__((address_space(3))) unsigned int*)l, 16, 0, 0);
}

// ---------------------------------------------------------------------------
// f32 -> bf16 streaming convert (n multiple of 8)
// ---------------------------------------------------------------------------
__global__ __launch_bounds__(256)
void f32_to_bf16(const float* __restrict__ in, unsigned short* __restrict__ o, size_t n)
{
    size_t i = ((size_t)blockIdx.x*256 + threadIdx.x)*8;
    if (i >= n) return;
    float4 a = *(const float4*)(in + i);
    float4 b = *(const float4*)(in + i + 4);
    uint4 v;
    v.x = (unsigned)f2bf(a.x) | ((unsigned)f2bf(a.y)<<16);
    v.y = (unsigned)f2bf(a.z) | ((unsigned)f2bf(a.w)<<16);
    v.z = (unsigned)f2bf(b.x) | ((unsigned)f2bf(b.y)<<16);
    v.w = (unsigned)f2bf(b.z) | ((unsigned)f2bf(b.w)<<16);
    *(uint4*)(o + i) = v;
}

// ---------------------------------------------------------------------------
// bf16 MFMA GEMM NT: C[M,N] = A[M,K] * B[N,K]^T, fp32 accumulate.
// 128x128 tile, BK=32, 256 threads (4 waves, 64x64 each, 4x4 x mfma 16x16x32).
// EPI=0: fp32 store to Cf (ldc=N).  EPI=2: bf16 store to Cb (ldc=N).
// EPI=1: in_proj xBC+dt epilogue (xbc fp32 + conv halo + softplus dt).
// M,K multiples of 128/32.  B rows may run past N (garbage cols never stored).
// ---------------------------------------------------------------------------
template<int EPI>
__global__ __launch_bounds__(256)
void gemm_mfma(const unsigned short* __restrict__ A,
               const unsigned short* __restrict__ B,
               int M, int N, int K,
               float* __restrict__ Cf, unsigned short* __restrict__ Cb,
               float* __restrict__ xbcout, float* __restrict__ dtout,
               const float* __restrict__ dt_bias, float* __restrict__ halo)
{
    __shared__ short As[128*32];
    __shared__ short Bs[128*32];
    const int tid  = threadIdx.x;
    const int wave = tid >> 6;
    const int lane = tid & 63;
    const int bm = blockIdx.y * 128;
    const int bn = blockIdx.x * 128;
    const int wr = (wave >> 1) * 64;
    const int wc = (wave & 1) * 64;
    const int quad = lane >> 4;
    const int l15  = lane & 15;

    f32x4 acc[4][4];
    #pragma unroll
    for (int i=0;i<4;i++)
        #pragma unroll
        for (int j=0;j<4;j++)
            acc[i][j] = (f32x4){0.f,0.f,0.f,0.f};

    const int srow = (lane >> 2);        // 0..15 within 16-row group
    const int skc  = (lane & 3) * 8;     // bf16 col offset within BK

    for (int k0 = 0; k0 < K; k0 += 32){
        #pragma unroll
        for (int s = 0; s < 4; s++){
            int t = wave*4 + s;          // 0..15 (wave-uniform)
            int r = (t & 7)*16 + srow;
            if (t < 8)
                gl2lds16(A + (size_t)(bm + r)*K + k0 + skc, &As[(t & 7)*512]);
            else
                gl2lds16(B + (size_t)(bn + r)*K + k0 + skc, &Bs[(t & 7)*512]);
        }
        __syncthreads();                 // drains vmcnt (global_load_lds)
        bf16x8 af[4], bg[4];
        #pragma unroll
        for (int i=0;i<4;i++)
            af[i] = *(const bf16x8*)&As[(wr + i*16 + l15)*32 + quad*8];
        #pragma unroll
        for (int j=0;j<4;j++)
            bg[j] = *(const bf16x8*)&Bs[(wc + j*16 + l15)*32 + quad*8];
        #pragma unroll
        for (int i=0;i<4;i++)
            #pragma unroll
            for (int j=0;j<4;j++)
                acc[i][j] = __builtin_amdgcn_mfma_f32_16x16x32_bf16(af[i], bg[j], acc[i][j], 0,0,0);
        __syncthreads();
    }

    // C/D layout: col = lane&15, row = quad*4 + reg   [m89-verified]
    if (EPI == 0){
        #pragma unroll
        for (int i=0;i<4;i++)
            #pragma unroll
            for (int j=0;j<4;j++){
                int col = bn + wc + j*16 + l15;
                #pragma unroll
                for (int r=0;r<4;r++){
                    int row = bm + wr + i*16 + quad*4 + r;
                    Cf[(size_t)row*N + col] = acc[i][j][r];
                }
            }
    } else if (EPI == 2){
        #pragma unroll
        for (int i=0;i<4;i++)
            #pragma unroll
            for (int j=0;j<4;j++){
                int col = bn + wc + j*16 + l15;
                #pragma unroll
                for (int r=0;r<4;r++){
                    int row = bm + wr + i*16 + quad*4 + r;
                    Cb[(size_t)row*N + col] = f2bf(acc[i][j][r]);
                }
            }
    } else {
        if (bn < CONVD){
            #pragma unroll
            for (int i=0;i<4;i++)
                #pragma unroll
                for (int r=0;r<4;r++){
                    int row = bm + wr + i*16 + quad*4 + r;
                    int rel = row & 63;
                    int seg = (row >> 6) + 1;
                    #pragma unroll
                    for (int j=0;j<4;j++){
                        int col = bn + wc + j*16 + l15;
                        float v = acc[i][j][r];
                        xbcout[(size_t)row*CONVD + col] = v;
                        if (rel >= 61 && seg < NCHUNK)
                            halo[((size_t)(seg*3 + (rel-61)))*CONVD + col] = v;
                    }
                }
        } else if (wc == 0){
            #pragma unroll
            for (int j=0;j<2;j++){
                int h = j*16 + l15;      // 0..31
                #pragma unroll
                for (int i=0;i<4;i++)
                    #pragma unroll
                    for (int r=0;r<4;r++){
                        int row = bm + wr + i*16 + quad*4 + r;
                        float t = acc[i][j][r] + dt_bias[h];
                        dtout[(size_t)row*NH + h] = (t > 20.f) ? t : log1pf(expf(t));
                    }
            }
        }
    }
}

// ---------------------------------------------------------------------------
// Causal depthwise conv(4) + bias + SiLU, in place, using pre-saved halos.
// ---------------------------------------------------------------------------
__global__ __launch_bounds__(256)
void conv_inplace(float* __restrict__ xbc, const float* __restrict__ halo,
                  const float* __restrict__ conv_w, const float* __restrict__ conv_b)
{
    int c = blockIdx.x*256 + threadIdx.x;
    if (c >= CONVD) return;
    int seg = blockIdx.y;
    const float w0=conv_w[c*4+0], w1=conv_w[c*4+1], w2=conv_w[c*4+2], w3=conv_w[c*4+3];
    const float bias = conv_b[c];
    float x0=0.f, x1=0.f, x2=0.f;
    if (seg > 0){
        const float* hp = halo + (size_t)(seg*3)*CONVD + c;
        x0 = hp[0]; x1 = hp[CONVD]; x2 = hp[2*CONVD];
    }
    float* p = xbc + (size_t)(seg*64)*CONVD + c;
    for (int i=0;i<64;i++){
        float x3 = *p;
        float v = fmaf(w0,x0,fmaf(w1,x1,fmaf(w2,x2,fmaf(w3,x3,bias))));
        *p = v * sigm(v);
        x0=x1; x1=x2; x2=x3; p += CONVD;
    }
}

// ---------------------------------------------------------------------------
// Intra-chunk: grid (c,h).  Y_diag + x*D in place; local states (bf16); acs.
// ---------------------------------------------------------------------------
__global__ __launch_bounds__(256)
void chunk_intra(float* __restrict__ xbc,
                 const float* __restrict__ dtbuf,
                 const float* __restrict__ A_log,
                 const float* __restrict__ Dvec,
                 unsigned short* __restrict__ states,
                 float* __restrict__ acsbuf,
                 float* __restrict__ csumbuf)
{
    const int c = blockIdx.x, h = blockIdx.y;
    __shared__ alignas(16) float CS[64][68];
    __shared__ alignas(16) float Bsh[64][68];
    __shared__ alignas(16) float Xsh[64][68];
    __shared__ float dt_sh[64];
    __shared__ float acs[64];
    __shared__ float dec_sh[64];
    const int tid = threadIdx.x;
    const size_t row0 = (size_t)(c*64) * CONVD;

    if (tid < 64) dt_sh[tid] = dtbuf[(size_t)(c*64 + tid)*NH + h];
    __syncthreads();
    if (tid == 0){
        float Ah = -expf(A_log[h]);
        float s = 0.f;
        for (int l=0;l<64;l++){ s = fmaf(Ah, dt_sh[l], s); acs[l] = s; }
    }
    {
        const int lr = tid >> 4;
        const int n4 = (tid & 15) * 4;
        #pragma unroll
        for (int i=0;i<4;i++){
            int l = lr + i*16;
            const float* rp = xbc + row0 + (size_t)l*CONVD;
            float4 cv = *(const float4*)(rp + DINNER + DSTATE + n4);
            float4 bv = *(const float4*)(rp + DINNER + n4);
            float4 xv = *(const float4*)(rp + h*HD + n4);
            float d = dt_sh[l];
            *(float4*)&CS[l][n4]  = cv;
            *(float4*)&Bsh[l][n4] = bv;
            *(float4*)&Xsh[l][n4] = make_float4(xv.x*d, xv.y*d, xv.z*d, xv.w*d);
        }
    }
    __syncthreads();
    const float acs63 = acs[63];
    if (tid < 64){
        dec_sh[tid] = expf(acs63 - acs[tid]);
        acsbuf[((size_t)h*64 + c)*64 + tid] = acs[tid];
    }
    if (tid == 0) csumbuf[(size_t)h*64 + c] = acs63;

    const int ty = tid >> 4, tx = tid & 15;
    const int l0 = ty*4, s0 = tx*4;

    float g[4][4] = {{0.f}};
    #pragma unroll 2
    for (int n=0;n<64;n+=4){
        float4 ca[4], bb[4];
        #pragma unroll
        for (int i=0;i<4;i++) ca[i] = *(const float4*)&CS[l0+i][n];
        #pragma unroll
        for (int j=0;j<4;j++) bb[j] = *(const float4*)&Bsh[s0+j][n];
        #pragma unroll
        for (int i=0;i<4;i++)
            #pragma unroll
            for (int j=0;j<4;j++)
                g[i][j] += ca[i].x*bb[j].x + ca[i].y*bb[j].y + ca[i].z*bb[j].z + ca[i].w*bb[j].w;
    }
    __syncthreads();
    #pragma unroll
    for (int i=0;i<4;i++){
        int l = l0 + i;
        #pragma unroll
        for (int j=0;j<4;j++){
            int s = s0 + j;
            CS[l][s] = (s <= l) ? g[i][j]*expf(acs[l]-acs[s]) : 0.f;
        }
    }
    __syncthreads();

    float yd[4][4] = {{0.f}};
    #pragma unroll 4
    for (int s=0;s<64;s++){
        float4 xv = *(const float4*)&Xsh[s][s0];
        float sc[4];
        #pragma unroll
        for (int i=0;i<4;i++) sc[i] = CS[l0+i][s];
        #pragma unroll
        for (int i=0;i<4;i++){
            yd[i][0] = fmaf(sc[i], xv.x, yd[i][0]);
            yd[i][1] = fmaf(sc[i], xv.y, yd[i][1]);
            yd[i][2] = fmaf(sc[i], xv.z, yd[i][2]);
            yd[i][3] = fmaf(sc[i], xv.w, yd[i][3]);
        }
    }

    float st[4][4] = {{0.f}};
    #pragma unroll 4
    for (int l=0;l<64;l++){
        float w = dec_sh[l];
        float4 xv = *(const float4*)&Xsh[l][l0];
        float4 bv = *(const float4*)&Bsh[l][s0];
        float wx0 = w*xv.x, wx1 = w*xv.y, wx2 = w*xv.z, wx3 = w*xv.w;
        st[0][0]=fmaf(wx0,bv.x,st[0][0]); st[0][1]=fmaf(wx0,bv.y,st[0][1]);
        st[0][2]=fmaf(wx0,bv.z,st[0][2]); st[0][3]=fmaf(wx0,bv.w,st[0][3]);
        st[1][0]=fmaf(wx1,bv.x,st[1][0]); st[1][1]=fmaf(wx1,bv.y,st[1][1]);
        st[1][2]=fmaf(wx1,bv.z,st[1][2]); st[1][3]=fmaf(wx1,bv.w,st[1][3]);
        st[2][0]=fmaf(wx2,bv.x,st[2][0]); st[2][1]=fmaf(wx2,bv.y,st[2][1]);
        st[2][2]=fmaf(wx2,bv.z,st[2][2]); st[2][3]=fmaf(wx2,bv.w,st[2][3]);
        st[3][0]=fmaf(wx3,bv.x,st[3][0]); st[3][1]=fmaf(wx3,bv.y,st[3][1]);
        st[3][2]=fmaf(wx3,bv.z,st[3][2]); st[3][3]=fmaf(wx3,bv.w,st[3][3]);
    }
    const size_t sbase = ((size_t)c*NH + h)*4096;
    #pragma unroll
    for (int i=0;i<4;i++){
        ushort4 sv;
        sv.x = f2bf(st[i][0]); sv.y = f2bf(st[i][1]);
        sv.z = f2bf(st[i][2]); sv.w = f2bf(st[i][3]);
        *(ushort4*)(states + sbase + (size_t)(l0+i)*64 + s0) = sv;
    }

    const float Dh = Dvec[h];
    #pragma unroll
    for (int i=0;i<4;i++){
        int l = l0 + i;
        float* rp = xbc + row0 + (size_t)l*CONVD + h*HD + s0;
        float4 xo = *(const float4*)rp;
        *(float4*)rp = make_float4(fmaf(xo.x,Dh,yd[i][0]),
                                   fmaf(xo.y,Dh,yd[i][1]),
                                   fmaf(xo.z,Dh,yd[i][2]),
                                   fmaf(xo.w,Dh,yd[i][3]));
    }
}

// ---------------------------------------------------------------------------
// Inter-chunk scan: grid (h).  bf16 states in place: local -> entering.
// ---------------------------------------------------------------------------
__global__ __launch_bounds__(256)
void chunk_scan(unsigned short* __restrict__ states,
                const float* __restrict__ csumbuf,
                const float* __restrict__ init_states)
{
    const int h = blockIdx.x;
    __shared__ float cs_sh[64];
    const int tid = threadIdx.x;
    if (tid < 64) cs_sh[tid] = csumbuf[(size_t)h*64 + tid];
    __syncthreads();
    float S[16];
    const float4* ip = (const float4*)(init_states + (size_t)h*4096 + tid*16);
    #pragma unroll
    for (int q=0;q<4;q++){
        float4 v = ip[q];
        S[q*4+0]=v.x; S[q*4+1]=v.y; S[q*4+2]=v.z; S[q*4+3]=v.w;
    }
    for (int z=0; z<NCHUNK; z++){
        unsigned short* sp = states + ((size_t)z*NH + h)*4096 + tid*16;
        float dec = expf(cs_sh[z]);
        uint4 a = *(uint4*)sp;
        uint4 b = *(uint4*)(sp+8);
        float loc[16];
        unsigned aa[8] = {a.x,a.y,a.z,a.w,b.x,b.y,b.z,b.w};
        #pragma unroll
        for (int q=0;q<8;q++){
            loc[q*2+0] = bf2f((unsigned short)(aa[q]&0xffff));
            loc[q*2+1] = bf2f((unsigned short)(aa[q]>>16));
        }
        uint4 oa, ob;
        unsigned ow[8];
        #pragma unroll
        for (int q=0;q<8;q++)
            ow[q] = (unsigned)f2bf(S[q*2]) | ((unsigned)f2bf(S[q*2+1])<<16);
        oa.x=ow[0]; oa.y=ow[1]; oa.z=ow[2]; oa.w=ow[3];
        ob.x=ow[4]; ob.y=ow[5]; ob.z=ow[6]; ob.w=ow[7];
        *(uint4*)sp = oa;
        *(uint4*)(sp+8) = ob;
        #pragma unroll
        for (int q=0;q<16;q++) S[q] = fmaf(dec, S[q], loc[q]);
    }
}

// ---------------------------------------------------------------------------
// Y_off: grid (c,h).  Y[l,p] += exp(acs[l]) * sum_n C[l,n]*S[p,n]  (S bf16)
// ---------------------------------------------------------------------------
__global__ __launch_bounds__(256)
void chunk_off(float* __restrict__ xbc,
               const unsigned short* __restrict__ states,
               const float* __restrict__ acsbuf)
{
    const int c = blockIdx.x, h = blockIdx.y;
    __shared__ alignas(16) float Csh[64][68];
    __shared__ alignas(16) float Ssh[64][68];
    __shared__ float ea[64];
    const int tid = threadIdx.x;
    const size_t row0 = (size_t)(c*64) * CONVD;
    const size_t sbase = ((size_t)c*NH + h)*4096;
    {
        const int lr = tid >> 4;
        const int n4 = (tid & 15)*4;
        #pragma unroll
        for (int i=0;i<4;i++){
            int r = lr + i*16;
            *(float4*)&Csh[r][n4] = *(const float4*)(xbc + row0 + (size_t)r*CONVD + DINNER + DSTATE + n4);
            ushort4 s4 = *(const ushort4*)(states + sbase + (size_t)r*64 + n4);
            Ssh[r][n4+0] = bf2f(s4.x); Ssh[r][n4+1] = bf2f(s4.y);
            Ssh[r][n4+2] = bf2f(s4.z); Ssh[r][n4+3] = bf2f(s4.w);
        }
    }
    if (tid < 64) ea[tid] = expf(acsbuf[((size_t)h*64 + c)*64 + tid]);
    __syncthreads();
    const int ty = tid >> 4, tx = tid & 15;
    const int l0 = ty*4, p0 = tx*4;
    float yo[4][4] = {{0.f}};
    #pragma unroll 2
    for (int n=0;n<64;n+=4){
        float4 cv[4], sv[4];
        #pragma unroll
        for (int i=0;i<4;i++) cv[i] = *(const float4*)&Csh[l0+i][n];
        #pragma unroll
        for (int j=0;j<4;j++) sv[j] = *(const float4*)&Ssh[p0+j][n];
        #pragma unroll
        for (int i=0;i<4;i++)
            #pragma unroll
            for (int j=0;j<4;j++)
                yo[i][j] += cv[i].x*sv[j].x + cv[i].y*sv[j].y + cv[i].z*sv[j].z + cv[i].w*sv[j].w;
    }
    #pragma unroll
    for (int i=0;i<4;i++){
        int l = l0 + i;
        float e = ea[l];
        float* rp = xbc + row0 + (size_t)l*CONVD + h*HD + p0;
        float4 o = *(const float4*)rp;
        *(float4*)rp = make_float4(fmaf(e,yo[i][0],o.x), fmaf(e,yo[i][1],o.y),
                                   fmaf(e,yo[i][2],o.z), fmaf(e,yo[i][3],o.w));
    }
}

// ---------------------------------------------------------------------------
// gate + RMSNorm: y = RMSNorm(Y*silu(z))*w, z bf16 in, y bf16 out (in place)
// ---------------------------------------------------------------------------
__global__ __launch_bounds__(256)
void gate_norm(const float* __restrict__ xbc, unsigned short* __restrict__ zbuf,
               const float* __restrict__ norm_w)
{
    const int m = blockIdx.x;
    const int tid = threadIdx.x;
    const float* Yp = xbc + (size_t)m*CONVD + tid*8;
    unsigned short* zp = zbuf + (size_t)m*DINNER + tid*8;
    float4 y0 = *(const float4*)Yp;
    float4 y1 = *(const float4*)(Yp+4);
    uint4 zv = *(const uint4*)zp;
    unsigned zz[4] = {zv.x, zv.y, zv.z, zv.w};
    float Yv[8] = {y0.x,y0.y,y0.z,y0.w,y1.x,y1.y,y1.z,y1.w};
    float g[8];
    float acc = 0.f;
    #pragma unroll
    for (int q=0;q<4;q++){
        float zl = bf2f((unsigned short)(zz[q]&0xffff));
        float zh = bf2f((unsigned short)(zz[q]>>16));
        g[q*2+0] = Yv[q*2+0] * zl * sigm(zl);
        g[q*2+1] = Yv[q*2+1] * zh * sigm(zh);
        acc += g[q*2]*g[q*2] + g[q*2+1]*g[q*2+1];
    }
    #pragma unroll
    for (int o=32;o>0;o>>=1) acc += __shfl_down(acc, o, 64);
    __shared__ float red[4];
    if ((tid & 63)==0) red[tid>>6] = acc;
    __syncthreads();
    float tot = red[0]+red[1]+red[2]+red[3];
    float scale = rsqrtf(tot * (1.f/2048.f) + 1e-5f);
    const float* nw = norm_w + tid*8;
    float4 w0 = *(const float4*)nw;
    float4 w1 = *(const float4*)(nw+4);
    float Wv[8] = {w0.x,w0.y,w0.z,w0.w,w1.x,w1.y,w1.z,w1.w};
    uint4 ov;
    unsigned ow[4];
    #pragma unroll
    for (int q=0;q<4;q++){
        unsigned short lo = f2bf(g[q*2+0]*scale*Wv[q*2+0]);
        unsigned short hi = f2bf(g[q*2+1]*scale*Wv[q*2+1]);
        ow[q] = (unsigned)lo | ((unsigned)hi<<16);
    }
    ov.x=ow[0]; ov.y=ow[1]; ov.z=ow[2]; ov.w=ow[3];
    *(uint4*)zp = ov;
}

// ---------------------------------------------------------------------------
extern "C" void kernel_launch(void* const* d_in, const int* in_sizes, int n_in,
                              void* d_out, int out_size, void* d_ws, size_t ws_size,
                              hipStream_t stream) {
    const float* u           = (const float*)d_in[0];
    const float* in_proj_w   = (const float*)d_in[1];
    const float* conv_w      = (const float*)d_in[2];
    const float* conv_b      = (const float*)d_in[3];
    const float* init_states = (const float*)d_in[4];
    const float* dt_bias     = (const float*)d_in[5];
    const float* A_log       = (const float*)d_in[6];
    const float* Dv          = (const float*)d_in[7];
    const float* norm_w      = (const float*)d_in[8];
    const float* out_proj_w  = (const float*)d_in[9];
    float* out = (float*)d_out;

    // Workspace (bytes, total 71.74 MB — under the proven 71.9 MB envelope):
    //  xbc fp32  35,651,584 | statesz bf16 16,777,216 (states C-E, z/y F-H)
    //  ubf bf16   8,388,608 (u A/F; w_out bf16 in H) | wibf bf16 8,716,288
    //  dtbuf fp32 524,288 | halo/acs union 1,671,168 | csum 8,192
    char* wsb = (char*)d_ws;
    float*          xbc     = (float*)(wsb);
    unsigned short* statesz = (unsigned short*)(wsb + 35651584);
    unsigned short* ubf     = (unsigned short*)(wsb + 35651584 + 16777216);
    unsigned short* wibf    = (unsigned short*)(wsb + 35651584 + 16777216 + 8388608);
    float*          dtbuf   = (float*)(wsb + 35651584 + 16777216 + 8388608 + 8716288);
    float*          haloacs = (float*)(wsb + 35651584 + 16777216 + 8388608 + 8716288 + 524288);
    float*          csumbuf = (float*)(wsb + 35651584 + 16777216 + 8388608 + 8716288 + 524288 + 1671168);
    unsigned short* woutbf  = ubf;       // phase H only (u dead after z-GEMM)
    float*          halo    = haloacs;   // phases A-B
    float*          acsbuf  = haloacs;   // phases C-E

    // in_proj weights -> bf16 (once)
    f32_to_bf16<<<dim3((4256*1024/8 + 255)/256), 256, 0, stream>>>(
        in_proj_w, wibf, (size_t)4256*1024);

    for (int b=0; b<BATCH; b++){
        const float* ub   = u   + (size_t)b*LSEQ*DMODEL;
        float*       outb = out + (size_t)b*LSEQ*DMODEL;

        // u -> bf16
        f32_to_bf16<<<dim3(LSEQ*DMODEL/8/256), 256, 0, stream>>>(
            ub, ubf, (size_t)LSEQ*DMODEL);
        // 1) in_proj xBC+dt cols (bf16 MFMA) + halo save + softplus dt
        gemm_mfma<1><<<dim3(18, LSEQ/128), 256, 0, stream>>>(
            ubf, wibf + (size_t)DINNER*DMODEL, LSEQ, NXD, DMODEL,
            nullptr, nullptr, xbc, dtbuf, dt_bias, halo);
        // 2) causal conv + silu in place
        conv_inplace<<<dim3((CONVD+255)/256, NCHUNK), 256, 0, stream>>>(
            xbc, halo, conv_w, conv_b);
        // 3) intra-chunk
        chunk_intra<<<dim3(NCHUNK, NH), 256, 0, stream>>>(
            xbc, dtbuf, A_log, Dv, statesz, acsbuf, csumbuf);
        // 4) inter-chunk scan
        chunk_scan<<<dim3(NH), 256, 0, stream>>>(statesz, csumbuf, init_states);
        // 5) Y_off accumulate in place
        chunk_off<<<dim3(NCHUNK, NH), 256, 0, stream>>>(xbc, statesz, acsbuf);
        // 6) in_proj z cols (bf16 MFMA) -> z bf16 (over statesz, now dead)
        gemm_mfma<2><<<dim3(DINNER/128, LSEQ/128), 256, 0, stream>>>(
            ubf, wibf, LSEQ, DINNER, DMODEL,
            nullptr, statesz, nullptr, nullptr, nullptr, nullptr);
        // 7) out_proj weights -> bf16 (into ubf, u now dead)
        f32_to_bf16<<<dim3(DINNER*DMODEL/8/256), 256, 0, stream>>>(
            out_proj_w, woutbf, (size_t)DINNER*DMODEL);
        // 8) gate + RMSNorm -> y bf16 in place over z
        gate_norm<<<dim3(LSEQ), 256, 0, stream>>>(xbc, statesz, norm_w);
        // 9) out_proj (bf16 MFMA) -> out fp32
        gemm_mfma<0><<<dim3(DMODEL/128, LSEQ/128), 256, 0, stream>>>(
            statesz, woutbf, LSEQ, DMODEL, DINNER,
            outb, nullptr, nullptr, nullptr, nullptr, nullptr);
    }
}

// Round 4
// 948.594 us; speedup vs baseline: 4.0872x; 1.2555x over previous
//
#include <hip/hip_runtime.h>
#include <math.h>

// Mamba2: D_MODEL=1024, EXPAND=2, HEADDIM=64, NGROUPS=1, D_STATE=64,
// D_CONV=4, CHUNK=64, B=4, L=4096.  Per-batch pipeline, MFMA everywhere.
#define BATCH  4
#define LSEQ   4096
#define DMODEL 1024
#define DINNER 2048
#define NH     32
#define HD     64
#define DSTATE 64
#define CONVD  2176      // D_INNER + 2*D_STATE
#define NXD    2208      // CONVD + NH
#define NCHUNK 64

typedef __attribute__((ext_vector_type(8))) short bf16x8;
typedef __attribute__((ext_vector_type(4))) float f32x4;

__device__ __forceinline__ float sigm(float x){ return 1.f/(1.f+expf(-x)); }

__device__ __forceinline__ unsigned short f2bf(float x){
    unsigned u = __float_as_uint(x);
    unsigned r = (u + 0x7fffu + ((u>>16)&1u)) >> 16;
    return (unsigned short)r;
}
__device__ __forceinline__ float bf2f(unsigned short h){
    return __uint_as_float(((unsigned)h)<<16);
}

// async global (16B/lane) -> LDS (wave-uniform base + lane*16)
__device__ __forceinline__ void gl2lds16(const unsigned short* g, short* l){
    __builtin_amdgcn_global_load_lds(
        (const __attribute__((address_space(1))) unsigned int*)g,
        (__attribute__((address_space(3))) unsigned int*)l, 16, 0, 0);
}

// ---------------------------------------------------------------------------
// f32 -> bf16 streaming convert (n multiple of 8)
// ---------------------------------------------------------------------------
__global__ __launch_bounds__(256)
void f32_to_bf16(const float* __restrict__ in, unsigned short* __restrict__ o, size_t n)
{
    size_t i = ((size_t)blockIdx.x*256 + threadIdx.x)*8;
    if (i >= n) return;
    float4 a = *(const float4*)(in + i);
    float4 b = *(const float4*)(in + i + 4);
    uint4 v;
    v.x = (unsigned)f2bf(a.x) | ((unsigned)f2bf(a.y)<<16);
    v.y = (unsigned)f2bf(a.z) | ((unsigned)f2bf(a.w)<<16);
    v.z = (unsigned)f2bf(b.x) | ((unsigned)f2bf(b.y)<<16);
    v.w = (unsigned)f2bf(b.z) | ((unsigned)f2bf(b.w)<<16);
    *(uint4*)(o + i) = v;
}

// ---------------------------------------------------------------------------
// bf16 MFMA GEMM NT (m97-style), 128x128 tile, BK=32, 4 waves, 4x4 16x16x32.
// EPI=0 fp32 store, EPI=2 bf16 store, EPI=1 in_proj xBC+dt epilogue.
// ---------------------------------------------------------------------------
template<int EPI>
__global__ __launch_bounds__(256)
void gemm_mfma(const unsigned short* __restrict__ A,
               const unsigned short* __restrict__ B,
               int M, int N, int K,
               float* __restrict__ Cf, unsigned short* __restrict__ Cb,
               float* __restrict__ xbcout, float* __restrict__ dtout,
               const float* __restrict__ dt_bias, float* __restrict__ halo)
{
    __shared__ short As[128*32];
    __shared__ short Bs[128*32];
    const int tid  = threadIdx.x;
    const int wave = tid >> 6;
    const int lane = tid & 63;
    const int bm = blockIdx.y * 128;
    const int bn = blockIdx.x * 128;
    const int wr = (wave >> 1) * 64;
    const int wc = (wave & 1) * 64;
    const int quad = lane >> 4;
    const int l15  = lane & 15;

    f32x4 acc[4][4];
    #pragma unroll
    for (int i=0;i<4;i++)
        #pragma unroll
        for (int j=0;j<4;j++)
            acc[i][j] = (f32x4){0.f,0.f,0.f,0.f};

    const int srow = (lane >> 2);
    const int skc  = (lane & 3) * 8;

    for (int k0 = 0; k0 < K; k0 += 32){
        #pragma unroll
        for (int s = 0; s < 4; s++){
            int t = wave*4 + s;
            int r = (t & 7)*16 + srow;
            if (t < 8)
                gl2lds16(A + (size_t)(bm + r)*K + k0 + skc, &As[(t & 7)*512]);
            else
                gl2lds16(B + (size_t)(bn + r)*K + k0 + skc, &Bs[(t & 7)*512]);
        }
        __syncthreads();
        bf16x8 af[4], bg[4];
        #pragma unroll
        for (int i=0;i<4;i++)
            af[i] = *(const bf16x8*)&As[(wr + i*16 + l15)*32 + quad*8];
        #pragma unroll
        for (int j=0;j<4;j++)
            bg[j] = *(const bf16x8*)&Bs[(wc + j*16 + l15)*32 + quad*8];
        #pragma unroll
        for (int i=0;i<4;i++)
            #pragma unroll
            for (int j=0;j<4;j++)
                acc[i][j] = __builtin_amdgcn_mfma_f32_16x16x32_bf16(af[i], bg[j], acc[i][j], 0,0,0);
        __syncthreads();
    }

    if (EPI == 0){
        #pragma unroll
        for (int i=0;i<4;i++)
            #pragma unroll
            for (int j=0;j<4;j++){
                int col = bn + wc + j*16 + l15;
                #pragma unroll
                for (int r=0;r<4;r++){
                    int row = bm + wr + i*16 + quad*4 + r;
                    Cf[(size_t)row*N + col] = acc[i][j][r];
                }
            }
    } else if (EPI == 2){
        #pragma unroll
        for (int i=0;i<4;i++)
            #pragma unroll
            for (int j=0;j<4;j++){
                int col = bn + wc + j*16 + l15;
                #pragma unroll
                for (int r=0;r<4;r++){
                    int row = bm + wr + i*16 + quad*4 + r;
                    Cb[(size_t)row*N + col] = f2bf(acc[i][j][r]);
                }
            }
    } else {
        if (bn < CONVD){
            #pragma unroll
            for (int i=0;i<4;i++)
                #pragma unroll
                for (int r=0;r<4;r++){
                    int row = bm + wr + i*16 + quad*4 + r;
                    int rel = row & 63;
                    int seg = (row >> 6) + 1;
                    #pragma unroll
                    for (int j=0;j<4;j++){
                        int col = bn + wc + j*16 + l15;
                        float v = acc[i][j][r];
                        xbcout[(size_t)row*CONVD + col] = v;
                        if (rel >= 61 && seg < NCHUNK)
                            halo[((size_t)(seg*3 + (rel-61)))*CONVD + col] = v;
                    }
                }
        } else if (wc == 0){
            #pragma unroll
            for (int j=0;j<2;j++){
                int h = j*16 + l15;
                #pragma unroll
                for (int i=0;i<4;i++)
                    #pragma unroll
                    for (int r=0;r<4;r++){
                        int row = bm + wr + i*16 + quad*4 + r;
                        float t = acc[i][j][r] + dt_bias[h];
                        dtout[(size_t)row*NH + h] = (t > 20.f) ? t : log1pf(expf(t));
                    }
            }
        }
    }
}

// ---------------------------------------------------------------------------
// Causal depthwise conv(4) + bias + SiLU, in place, using pre-saved halos.
// ---------------------------------------------------------------------------
__global__ __launch_bounds__(256)
void conv_inplace(float* __restrict__ xbc, const float* __restrict__ halo,
                  const float* __restrict__ conv_w, const float* __restrict__ conv_b)
{
    int c = blockIdx.x*256 + threadIdx.x;
    if (c >= CONVD) return;
    int seg = blockIdx.y;
    const float w0=conv_w[c*4+0], w1=conv_w[c*4+1], w2=conv_w[c*4+2], w3=conv_w[c*4+3];
    const float bias = conv_b[c];
    float x0=0.f, x1=0.f, x2=0.f;
    if (seg > 0){
        const float* hp = halo + (size_t)(seg*3)*CONVD + c;
        x0 = hp[0]; x1 = hp[CONVD]; x2 = hp[2*CONVD];
    }
    float* p = xbc + (size_t)(seg*64)*CONVD + c;
    for (int i=0;i<64;i++){
        float x3 = *p;
        float v = fmaf(w0,x0,fmaf(w1,x1,fmaf(w2,x2,fmaf(w3,x3,bias))));
        *p = v * sigm(v);
        x0=x1; x1=x2; x2=x3; p += CONVD;
    }
}

// ---------------------------------------------------------------------------
// states_intra: per (c,h).  loc_state[p][n] = sum_l x[l][p]*dt[l]*dec[l]*B[l][n]
// via NT MFMA on transposed bf16 LDS tiles.  Also writes acs + csum.
// ---------------------------------------------------------------------------
__global__ __launch_bounds__(256)
void states_intra(const float* __restrict__ xbc,
                  const float* __restrict__ dtbuf,
                  const float* __restrict__ A_log,
                  unsigned short* __restrict__ locst,
                  float* __restrict__ acsbuf,
                  float* __restrict__ csumbuf)
{
    const int c = blockIdx.x, h = blockIdx.y;
    __shared__ unsigned short XT[64*72];   // XT[p][l] = x[l][p] (raw)
    __shared__ unsigned short BT[64*72];   // BT[n][l] = B[l][n]*dec[l]*dt[l]
    __shared__ float dt_sh[64], acs_sh[64], w_sh[64];
    const int tid = threadIdx.x;
    const size_t row0 = (size_t)(c*64)*CONVD;

    if (tid < 64) dt_sh[tid] = dtbuf[(size_t)(c*64+tid)*NH + h];
    __syncthreads();
    if (tid == 0){
        float Ah = -expf(A_log[h]); float s = 0.f;
        for (int l=0;l<64;l++){ s = fmaf(Ah, dt_sh[l], s); acs_sh[l] = s; }
    }
    __syncthreads();
    const float a63 = acs_sh[63];
    if (tid < 64){
        float a = acs_sh[tid];
        acsbuf[((size_t)h*64 + c)*64 + tid] = a;
        w_sh[tid] = expf(a63 - a) * dt_sh[tid];
    }
    if (tid == 0) csumbuf[(size_t)h*64 + c] = a63;
    __syncthreads();

    {   // stage transposed tiles
        const int l  = tid >> 2;
        const int f4 = tid & 3;
        const float* xr = xbc + row0 + (size_t)l*CONVD;
        const float w = w_sh[l];
        #pragma unroll
        for (int q=0;q<4;q++){
            int col = f4*4 + q*16;
            float4 xv = *(const float4*)(xr + h*HD + col);
            float4 bv = *(const float4*)(xr + DINNER + col);
            XT[(col+0)*72 + l] = f2bf(xv.x);
            XT[(col+1)*72 + l] = f2bf(xv.y);
            XT[(col+2)*72 + l] = f2bf(xv.z);
            XT[(col+3)*72 + l] = f2bf(xv.w);
            BT[(col+0)*72 + l] = f2bf(bv.x*w);
            BT[(col+1)*72 + l] = f2bf(bv.y*w);
            BT[(col+2)*72 + l] = f2bf(bv.z*w);
            BT[(col+3)*72 + l] = f2bf(bv.w*w);
        }
    }
    __syncthreads();

    const int wave = tid >> 6, lane = tid & 63;
    const int quad = lane >> 4, l15 = lane & 15;
    f32x4 acc[4];
    #pragma unroll
    for (int j=0;j<4;j++) acc[j] = (f32x4){0.f,0.f,0.f,0.f};
    #pragma unroll
    for (int ks=0;ks<2;ks++){
        bf16x8 af = *(const bf16x8*)&XT[(wave*16 + l15)*72 + ks*32 + quad*8];
        #pragma unroll
        for (int j=0;j<4;j++){
            bf16x8 bf = *(const bf16x8*)&BT[(j*16 + l15)*72 + ks*32 + quad*8];
            acc[j] = __builtin_amdgcn_mfma_f32_16x16x32_bf16(af, bf, acc[j], 0,0,0);
        }
    }
    const size_t sbase = ((size_t)c*NH + h)*4096;
    #pragma unroll
    for (int j=0;j<4;j++)
        #pragma unroll
        for (int r=0;r<4;r++){
            int p = wave*16 + quad*4 + r;
            int n = j*16 + l15;
            locst[sbase + (size_t)p*64 + n] = f2bf(acc[j][r]);
        }
}

// ---------------------------------------------------------------------------
// Inter-chunk scan, in place (loc -> entering), grid (NH,2).
// Group-of-8 batched loads to pipeline the 64-step dependency chain.
// ---------------------------------------------------------------------------
__global__ __launch_bounds__(256)
void chunk_scan(unsigned short* __restrict__ states,
                const float* __restrict__ csumbuf,
                const float* __restrict__ init_states)
{
    const int h = blockIdx.x, half = blockIdx.y;
    __shared__ float cs_sh[64];
    const int tid = threadIdx.x;
    if (tid < 64) cs_sh[tid] = csumbuf[(size_t)h*64 + tid];
    __syncthreads();
    const int e0 = half*2048 + tid*8;
    float S[8];
    {
        const float4* ip = (const float4*)(init_states + (size_t)h*4096 + e0);
        float4 v0 = ip[0], v1 = ip[1];
        S[0]=v0.x; S[1]=v0.y; S[2]=v0.z; S[3]=v0.w;
        S[4]=v1.x; S[5]=v1.y; S[6]=v1.z; S[7]=v1.w;
    }
    for (int zg=0; zg<8; zg++){
        uint4 L[8];
        #pragma unroll
        for (int k=0;k<8;k++)
            L[k] = *(const uint4*)(states + ((size_t)(zg*8+k)*NH + h)*4096 + e0);
        #pragma unroll
        for (int k=0;k<8;k++){
            int z = zg*8 + k;
            float dec = expf(cs_sh[z]);
            uint4 o;
            o.x = (unsigned)f2bf(S[0]) | ((unsigned)f2bf(S[1])<<16);
            o.y = (unsigned)f2bf(S[2]) | ((unsigned)f2bf(S[3])<<16);
            o.z = (unsigned)f2bf(S[4]) | ((unsigned)f2bf(S[5])<<16);
            o.w = (unsigned)f2bf(S[6]) | ((unsigned)f2bf(S[7])<<16);
            *(uint4*)(states + ((size_t)z*NH + h)*4096 + e0) = o;
            unsigned a[4] = {L[k].x, L[k].y, L[k].z, L[k].w};
            #pragma unroll
            for (int q=0;q<4;q++){
                float lo = bf2f((unsigned short)(a[q]&0xffff));
                float hi = bf2f((unsigned short)(a[q]>>16));
                S[q*2+0] = fmaf(dec, S[q*2+0], lo);
                S[q*2+1] = fmaf(dec, S[q*2+1], hi);
            }
        }
    }
}

// ---------------------------------------------------------------------------
// y_fused: per (c,h).  G = C·B^T (MFMA) -> score (mask/decay/dt, bf16 LDS)
// -> Y = score·x + (ea·C)·S_enter^T + x·D, single write over x region.
// ---------------------------------------------------------------------------
__global__ __launch_bounds__(256)
void y_fused(float* __restrict__ xbc,
             const float* __restrict__ dtbuf,
             const unsigned short* __restrict__ entst,
             const float* __restrict__ acsbuf,
             const float* __restrict__ Dvec)
{
    const int c = blockIdx.x, h = blockIdx.y;
    __shared__ unsigned short Cr[64*72];   // C raw
    __shared__ unsigned short Ce[64*72];   // C * ea[l]
    __shared__ unsigned short Bm[64*72];   // B raw; reused for score
    __shared__ unsigned short XT[64*72];   // x^T
    __shared__ unsigned short Sv[64*72];   // entering states [p][n]
    __shared__ float acs_sh[64], dt_sh[64], ea_sh[64];
    const int tid = threadIdx.x;
    const size_t row0 = (size_t)(c*64)*CONVD;
    const size_t sbase = ((size_t)c*NH + h)*4096;

    if (tid < 64){
        float a = acsbuf[((size_t)h*64 + c)*64 + tid];
        acs_sh[tid] = a;
        ea_sh[tid]  = expf(a);
        dt_sh[tid]  = dtbuf[(size_t)(c*64 + tid)*NH + h];
    }
    __syncthreads();

    {   // stage tiles
        const int l  = tid >> 2;
        const int f4 = tid & 3;
        const float* xr = xbc + row0 + (size_t)l*CONVD;
        const float el = ea_sh[l];
        #pragma unroll
        for (int q=0;q<4;q++){
            int col = f4*4 + q*16;
            float4 cv = *(const float4*)(xr + DINNER + DSTATE + col);
            float4 bv = *(const float4*)(xr + DINNER + col);
            float4 xv = *(const float4*)(xr + h*HD + col);
            unsigned short* cr = &Cr[l*72 + col];
            cr[0]=f2bf(cv.x); cr[1]=f2bf(cv.y); cr[2]=f2bf(cv.z); cr[3]=f2bf(cv.w);
            unsigned short* ce = &Ce[l*72 + col];
            ce[0]=f2bf(cv.x*el); ce[1]=f2bf(cv.y*el); ce[2]=f2bf(cv.z*el); ce[3]=f2bf(cv.w*el);
            unsigned short* bm = &Bm[l*72 + col];
            bm[0]=f2bf(bv.x); bm[1]=f2bf(bv.y); bm[2]=f2bf(bv.z); bm[3]=f2bf(bv.w);
            XT[(col+0)*72 + l] = f2bf(xv.x);
            XT[(col+1)*72 + l] = f2bf(xv.y);
            XT[(col+2)*72 + l] = f2bf(xv.z);
            XT[(col+3)*72 + l] = f2bf(xv.w);
            *(uint2*)&Sv[l*72 + col] = *(const uint2*)(entst + sbase + (size_t)l*64 + col);
        }
    }
    __syncthreads();

    const int wave = tid >> 6, lane = tid & 63;
    const int quad = lane >> 4, l15 = lane & 15;

    // G[l][s] = sum_n C[l][n] * B[s][n]   (wave rows l = wave*16..)
    f32x4 g[4];
    #pragma unroll
    for (int j=0;j<4;j++) g[j] = (f32x4){0.f,0.f,0.f,0.f};
    #pragma unroll
    for (int ks=0;ks<2;ks++){
        bf16x8 af = *(const bf16x8*)&Cr[(wave*16 + l15)*72 + ks*32 + quad*8];
        #pragma unroll
        for (int j=0;j<4;j++){
            bf16x8 bf = *(const bf16x8*)&Bm[(j*16 + l15)*72 + ks*32 + quad*8];
            g[j] = __builtin_amdgcn_mfma_f32_16x16x32_bf16(af, bf, g[j], 0,0,0);
        }
    }
    __syncthreads();   // all Bm reads done before overwrite with score

    // score[l][s] = (s<=l) ? G * exp(acs[l]-acs[s]) * dt[s] : 0
    #pragma unroll
    for (int j=0;j<4;j++)
        #pragma unroll
        for (int r=0;r<4;r++){
            int l = wave*16 + quad*4 + r;
            int s = j*16 + l15;
            float v = (s <= l) ? g[j][r]*expf(acs_sh[l]-acs_sh[s])*dt_sh[s] : 0.f;
            Bm[l*72 + s] = f2bf(v);
        }
    __syncthreads();

    // Y[l][p] = sum_s score[l][s]*x[s][p] + sum_n eaC[l][n]*S[p][n]
    f32x4 y[4];
    #pragma unroll
    for (int j=0;j<4;j++) y[j] = (f32x4){0.f,0.f,0.f,0.f};
    #pragma unroll
    for (int ks=0;ks<2;ks++){
        bf16x8 a1 = *(const bf16x8*)&Bm[(wave*16 + l15)*72 + ks*32 + quad*8];
        bf16x8 a2 = *(const bf16x8*)&Ce[(wave*16 + l15)*72 + ks*32 + quad*8];
        #pragma unroll
        for (int j=0;j<4;j++){
            bf16x8 b1 = *(const bf16x8*)&XT[(j*16 + l15)*72 + ks*32 + quad*8];
            bf16x8 b2 = *(const bf16x8*)&Sv[(j*16 + l15)*72 + ks*32 + quad*8];
            y[j] = __builtin_amdgcn_mfma_f32_16x16x32_bf16(a1, b1, y[j], 0,0,0);
            y[j] = __builtin_amdgcn_mfma_f32_16x16x32_bf16(a2, b2, y[j], 0,0,0);
        }
    }

    // epilogue: Y += x*D, single write over x region (fp32 x from global)
    const float Dh = Dvec[h];
    #pragma unroll
    for (int j=0;j<4;j++)
        #pragma unroll
        for (int r=0;r<4;r++){
            int l = wave*16 + quad*4 + r;
            int p = j*16 + l15;
            float* xp = xbc + row0 + (size_t)l*CONVD + h*HD + p;
            float xv = *xp;
            *xp = fmaf(xv, Dh, y[j][r]);
        }
}

// ---------------------------------------------------------------------------
// gate + RMSNorm: y = RMSNorm(Y*silu(z))*w, z bf16 in, y bf16 out (in place)
// ---------------------------------------------------------------------------
__global__ __launch_bounds__(256)
void gate_norm(const float* __restrict__ xbc, unsigned short* __restrict__ zbuf,
               const float* __restrict__ norm_w)
{
    const int m = blockIdx.x;
    const int tid = threadIdx.x;
    const float* Yp = xbc + (size_t)m*CONVD + tid*8;
    unsigned short* zp = zbuf + (size_t)m*DINNER + tid*8;
    float4 y0 = *(const float4*)Yp;
    float4 y1 = *(const float4*)(Yp+4);
    uint4 zv = *(const uint4*)zp;
    unsigned zz[4] = {zv.x, zv.y, zv.z, zv.w};
    float Yv[8] = {y0.x,y0.y,y0.z,y0.w,y1.x,y1.y,y1.z,y1.w};
    float g[8];
    float acc = 0.f;
    #pragma unroll
    for (int q=0;q<4;q++){
        float zl = bf2f((unsigned short)(zz[q]&0xffff));
        float zh = bf2f((unsigned short)(zz[q]>>16));
        g[q*2+0] = Yv[q*2+0] * zl * sigm(zl);
        g[q*2+1] = Yv[q*2+1] * zh * sigm(zh);
        acc += g[q*2]*g[q*2] + g[q*2+1]*g[q*2+1];
    }
    #pragma unroll
    for (int o=32;o>0;o>>=1) acc += __shfl_down(acc, o, 64);
    __shared__ float red[4];
    if ((tid & 63)==0) red[tid>>6] = acc;
    __syncthreads();
    float tot = red[0]+red[1]+red[2]+red[3];
    float scale = rsqrtf(tot * (1.f/2048.f) + 1e-5f);
    const float* nw = norm_w + tid*8;
    float4 w0 = *(const float4*)nw;
    float4 w1 = *(const float4*)(nw+4);
    float Wv[8] = {w0.x,w0.y,w0.z,w0.w,w1.x,w1.y,w1.z,w1.w};
    uint4 ov;
    unsigned ow[4];
    #pragma unroll
    for (int q=0;q<4;q++){
        unsigned short lo = f2bf(g[q*2+0]*scale*Wv[q*2+0]);
        unsigned short hi = f2bf(g[q*2+1]*scale*Wv[q*2+1]);
        ow[q] = (unsigned)lo | ((unsigned)hi<<16);
    }
    ov.x=ow[0]; ov.y=ow[1]; ov.z=ow[2]; ov.w=ow[3];
    *(uint4*)zp = ov;
}

// ---------------------------------------------------------------------------
extern "C" void kernel_launch(void* const* d_in, const int* in_sizes, int n_in,
                              void* d_out, int out_size, void* d_ws, size_t ws_size,
                              hipStream_t stream) {
    const float* u           = (const float*)d_in[0];
    const float* in_proj_w   = (const float*)d_in[1];
    const float* conv_w      = (const float*)d_in[2];
    const float* conv_b      = (const float*)d_in[3];
    const float* init_states = (const float*)d_in[4];
    const float* dt_bias     = (const float*)d_in[5];
    const float* A_log       = (const float*)d_in[6];
    const float* Dv          = (const float*)d_in[7];
    const float* norm_w      = (const float*)d_in[8];
    const float* out_proj_w  = (const float*)d_in[9];
    float* out = (float*)d_out;

    // Workspace layout identical to round 3 (71.74 MB proven envelope)
    char* wsb = (char*)d_ws;
    float*          xbc     = (float*)(wsb);
    unsigned short* statesz = (unsigned short*)(wsb + 35651584);
    unsigned short* ubf     = (unsigned short*)(wsb + 35651584 + 16777216);
    unsigned short* wibf    = (unsigned short*)(wsb + 35651584 + 16777216 + 8388608);
    float*          dtbuf   = (float*)(wsb + 35651584 + 16777216 + 8388608 + 8716288);
    float*          haloacs = (float*)(wsb + 35651584 + 16777216 + 8388608 + 8716288 + 524288);
    float*          csumbuf = (float*)(wsb + 35651584 + 16777216 + 8388608 + 8716288 + 524288 + 1671168);
    unsigned short* woutbf  = ubf;       // phase H only (u dead after z-GEMM)
    float*          halo    = haloacs;   // conv phases
    float*          acsbuf  = haloacs;   // chunk phases

    f32_to_bf16<<<dim3((4256*1024/8 + 255)/256), 256, 0, stream>>>(
        in_proj_w, wibf, (size_t)4256*1024);

    for (int b=0; b<BATCH; b++){
        const float* ub   = u   + (size_t)b*LSEQ*DMODEL;
        float*       outb = out + (size_t)b*LSEQ*DMODEL;

        f32_to_bf16<<<dim3(LSEQ*DMODEL/8/256), 256, 0, stream>>>(
            ub, ubf, (size_t)LSEQ*DMODEL);
        // 1) in_proj xBC+dt cols + halo save + softplus dt
        gemm_mfma<1><<<dim3(18, LSEQ/128), 256, 0, stream>>>(
            ubf, wibf + (size_t)DINNER*DMODEL, LSEQ, NXD, DMODEL,
            nullptr, nullptr, xbc, dtbuf, dt_bias, halo);
        // 2) causal conv + silu in place
        conv_inplace<<<dim3((CONVD+255)/256, NCHUNK), 256, 0, stream>>>(
            xbc, halo, conv_w, conv_b);
        // 3) local states (MFMA) + acs/csum
        states_intra<<<dim3(NCHUNK, NH), 256, 0, stream>>>(
            xbc, dtbuf, A_log, statesz, acsbuf, csumbuf);
        // 4) inter-chunk scan in place (loc -> entering)
        chunk_scan<<<dim3(NH, 2), 256, 0, stream>>>(statesz, csumbuf, init_states);
        // 5) fused Y = Y_diag + Y_off + x*D (MFMA), single write
        y_fused<<<dim3(NCHUNK, NH), 256, 0, stream>>>(
            xbc, dtbuf, statesz, acsbuf, Dv);
        // 6) in_proj z cols -> z bf16 (over statesz, now dead)
        gemm_mfma<2><<<dim3(DINNER/128, LSEQ/128), 256, 0, stream>>>(
            ubf, wibf, LSEQ, DINNER, DMODEL,
            nullptr, statesz, nullptr, nullptr, nullptr, nullptr);
        // 7) out_proj weights -> bf16 (into ubf, u now dead)
        f32_to_bf16<<<dim3(DINNER*DMODEL/8/256), 256, 0, stream>>>(
            out_proj_w, woutbf, (size_t)DINNER*DMODEL);
        // 8) gate + RMSNorm -> y bf16 in place over z
        gate_norm<<<dim3(LSEQ), 256, 0, stream>>>(xbc, statesz, norm_w);
        // 9) out_proj -> out fp32
        gemm_mfma<0><<<dim3(DMODEL/128, LSEQ/128), 256, 0, stream>>>(
            statesz, woutbf, LSEQ, DMODEL, DINNER,
            outb, nullptr, nullptr, nullptr, nullptr, nullptr);
    }
}